// Round 6
// baseline (192.570 us; speedup 1.0000x reference)
//
#include <hip/hip_runtime.h>

// AdaptedGaussianConditional: v = inputs - means; nearest-codebook symbol via
// exact lower_bound semantics (tie -> lower index); dequant = codebook[sym] + means.
// Outputs concatenated: [dequant fp32 N | symbols-as-f32 N].
//
// R6 == R5 with compile fix: __builtin_nontemporal_store requires a NATIVE
// vector type, not HIP's float4 class -> use ext_vector_type(4).
// R5: (a) nontemporal float4 stores for both outputs (write-once data; bypass
// L2/L3 allocate & churn); (b) NB 1024->512 cuts LDS 33.8->17.4 KB -> 8
// blocks/CU occupancy cap. Hot path unchanged from R4: branchless 2-split LUT,
// sel=(p0<v)+(p1<v), 2 ds_read_b128/element.

#define LVL 256
#define NB  512
#define QPT 4

typedef float f32x4 __attribute__((ext_vector_type(4)));   // native vector for nt-store

// Shared by build & main kernels — MUST be bit-identical in both.
// Weakly monotone in v  =>  bucket(uv[j]) < bucket(v) implies uv[j] < v,
// and bucket(uv[j]) > bucket(v) implies uv[j] > v (exactness of fallback scan).
__device__ __forceinline__ int bucket_of(float v, float lo, float scale) {
    int b = (int)floorf((v - lo) * scale);
    return min(max(b, 0), NB - 1);
}

// ---------------- build kernel: NB/256 blocks ----------------
// lutA[b] = {p0, p1, c0, c1}   lutB[b] = {c2, c3, unused, basepack}
// basepack int >= 0 : branchless entry, base = basepack + sel
// basepack int <  0 : fallback, exact scan start = -basepack - 1
__global__ __launch_bounds__(256) void agc_build_lut(
    const float* __restrict__ uv, float4* __restrict__ lutA, float4* __restrict__ lutB)
{
    __shared__ float s_uv[LVL];
    __shared__ int   s_b[LVL];
    int t = threadIdx.x;
    s_uv[t] = uv[t];
    __syncthreads();
    const float lo    = s_uv[0];
    const float scale = (float)NB / (s_uv[LVL - 1] - lo);
    s_b[t] = bucket_of(s_uv[t], lo, scale);
    __syncthreads();

    int b = blockIdx.x * 256 + t;
    if (b >= NB) return;

    int A = 0, cnt = 0;
    for (int j = 0; j < LVL; ++j) {      // broadcast reads, cheap
        int bj = s_b[j];
        A   += (bj <  b);
        cnt += (bj == b);
    }

    const float INF = __builtin_inff();
    float4 ea, eb;
    if (cnt == 0) {
        // constant clipped lower_bound over the whole bucket
        int idx = min(max(A, 1), LVL - 1);
        ea = make_float4(INF, INF, s_uv[idx - 1], s_uv[idx]);
        eb = make_float4(0.f, 0.f, 0.f, __int_as_float(idx - 1));
    } else if (cnt <= 2 && A >= 1 && A + cnt <= LVL - 1) {
        // no clipping anywhere in range: idx = A + sel, sel in [0, cnt]
        float p0 = s_uv[A];
        float p1 = (cnt >= 2) ? s_uv[A + 1] : INF;
        float c0 = s_uv[A - 1];
        float c1 = s_uv[A];
        float c2 = s_uv[A + 1];                            // A+1 <= 255
        float c3 = (A + 2 <= LVL - 1) ? s_uv[A + 2] : 0.f; // used only if cnt==2
        ea = make_float4(p0, p1, c0, c1);
        eb = make_float4(c2, c3, 0.f, __int_as_float(A - 1));
    } else {
        // rare: >=3 points or clipped edge region -> exact masked scan
        ea = make_float4(0.f, 0.f, 0.f, 0.f);
        eb = make_float4(0.f, 0.f, 0.f, __int_as_float(-(A + 1)));
    }
    lutA[b] = ea;
    lutB[b] = eb;
}

// ---------------- main kernel ----------------
__global__ __launch_bounds__(256) void agc_quant_lut(
    const float* __restrict__ inputs,
    const float* __restrict__ means,
    const float* __restrict__ uv,
    const float4* __restrict__ lutA,
    const float4* __restrict__ lutB,
    float* __restrict__ out_deq,
    float* __restrict__ out_sym,
    int n4, int n, int nfull)
{
    __shared__ float  s_uv[LVL];
    __shared__ float4 s_A[NB];
    __shared__ float4 s_B[NB];

    int t = threadIdx.x;
    s_uv[t] = uv[t];
    #pragma unroll
    for (int q = 0; q < NB / 256; ++q) {
        int j = q * 256 + t;
        s_A[j] = lutA[j];
        s_B[j] = lutB[j];
    }
    __syncthreads();

    const float lo    = s_uv[0];
    const float scale = (float)NB / (s_uv[LVL - 1] - lo);

    const int i0 = blockIdx.x * (256 * QPT) + t;
    const bool full = (blockIdx.x < nfull);

    // ---- load phase: all 2*QPT global loads in flight ----
    float4 in[QPT], mn[QPT];
    if (full) {
        #pragma unroll
        for (int k = 0; k < QPT; ++k) {
            int i = i0 + k * 256;
            in[k] = reinterpret_cast<const float4*>(inputs)[i];
            mn[k] = reinterpret_cast<const float4*>(means)[i];
        }
    } else {
        #pragma unroll
        for (int k = 0; k < QPT; ++k) {
            int i = i0 + k * 256;
            if (i < n4) {
                in[k] = reinterpret_cast<const float4*>(inputs)[i];
                mn[k] = reinterpret_cast<const float4*>(means)[i];
            }
        }
    }

    // ---- compute + store ----
    #pragma unroll
    for (int k = 0; k < QPT; ++k) {
        int i = i0 + k * 256;
        if (!full && i >= n4) continue;

        float vs[4] = {in[k].x - mn[k].x, in[k].y - mn[k].y,
                       in[k].z - mn[k].z, in[k].w - mn[k].w};
        float ms[4] = {mn[k].x, mn[k].y, mn[k].z, mn[k].w};
        float dq[4], sy[4];

        #pragma unroll
        for (int e = 0; e < 4; ++e) {
            float v = vs[e];
            int b = bucket_of(v, lo, scale);

            float4 A4 = s_A[b];          // {p0, p1, c0, c1}
            float4 B4 = s_B[b];          // {c2, c3, -, basepack}
            int bp = __float_as_int(B4.w);

            float left, right;
            int base;
            if (bp >= 0) {
                // branchless (compiler -> cndmask): sel in {0,1,2}
                int sel = (A4.x < v) + (A4.y < v);
                left  = (sel == 0) ? A4.z : ((sel == 1) ? A4.w : B4.x);
                right = (sel == 0) ? A4.w : ((sel == 1) ? B4.x : B4.y);
                base  = bp + sel;
            } else {
                // rare masked path: exact lower_bound scan, start is valid
                int s = -bp - 1;
                while (s < LVL && s_uv[s] < v) ++s;
                int idx = min(max(s, 1), LVL - 1);
                left  = s_uv[idx - 1];
                right = s_uv[idx];
                base  = idx - 1;
            }

            bool tl = (fabsf(v - left) <= fabsf(v - right));  // identical to reference
            sy[e] = (float)(base + (tl ? 0 : 1));
            dq[e] = (tl ? left : right) + ms[e];
        }

        // nontemporal: outputs are write-once, never re-read -> bypass cache allocate
        f32x4 dqv = {dq[0], dq[1], dq[2], dq[3]};
        f32x4 syv = {sy[0], sy[1], sy[2], sy[3]};
        __builtin_nontemporal_store(dqv, reinterpret_cast<f32x4*>(out_deq) + i);
        __builtin_nontemporal_store(syv, reinterpret_cast<f32x4*>(out_sym) + i);
    }

    // tail (n % 4 != 0) — n here is 12.58M, rem = 0
    if (blockIdx.x == 0 && t == 0) {
        for (int j = n4 * 4; j < n; ++j) {
            float m = means[j];
            float v = inputs[j] - m;
            int l = 0, h = LVL;
            for (int s = 0; s < 8; ++s) {
                int mm = (l + h) >> 1;
                bool r = (s_uv[mm] < v);
                l = r ? (mm + 1) : l;
                h = r ? h : mm;
            }
            int idx = min(max(l, 1), LVL - 1);
            float left = s_uv[idx - 1], right = s_uv[idx];
            bool tl = fabsf(v - left) <= fabsf(v - right);
            out_deq[j] = (tl ? left : right) + m;
            out_sym[j] = (float)(tl ? idx - 1 : idx);
        }
    }
}

// ---------------- safety fallback (no/short workspace): binary-search kernel ----
__global__ __launch_bounds__(256) void agc_quant_fallback(
    const float* __restrict__ inputs,
    const float* __restrict__ means,
    const float* __restrict__ uv,
    float* __restrict__ out_deq,
    float* __restrict__ out_sym,
    int n4, int n)
{
    __shared__ float s_uv[LVL];
    s_uv[threadIdx.x] = uv[threadIdx.x];
    __syncthreads();

    int i = blockIdx.x * blockDim.x + threadIdx.x;
    if (i < n4) {
        float4 in = reinterpret_cast<const float4*>(inputs)[i];
        float4 mn = reinterpret_cast<const float4*>(means)[i];
        float vs[4] = {in.x - mn.x, in.y - mn.y, in.z - mn.z, in.w - mn.w};
        float ms[4] = {mn.x, mn.y, mn.z, mn.w};
        float dq[4], sy[4];
        #pragma unroll
        for (int k = 0; k < 4; ++k) {
            float v = vs[k];
            int lo = 0, hi = LVL;
            #pragma unroll
            for (int s = 0; s < 8; ++s) {
                int mid = (lo + hi) >> 1;
                bool r = (s_uv[mid] < v);
                lo = r ? (mid + 1) : lo;
                hi = r ? hi : mid;
            }
            int idx = min(max(lo, 1), LVL - 1);
            float left = s_uv[idx - 1], right = s_uv[idx];
            bool tl = (fabsf(v - left) <= fabsf(v - right));
            sy[k] = (float)(tl ? idx - 1 : idx);
            dq[k] = (tl ? left : right) + ms[k];
        }
        reinterpret_cast<float4*>(out_deq)[i] = make_float4(dq[0], dq[1], dq[2], dq[3]);
        reinterpret_cast<float4*>(out_sym)[i] = make_float4(sy[0], sy[1], sy[2], sy[3]);
    }
    if (blockIdx.x == 0 && threadIdx.x == 0) {
        for (int j = n4 * 4; j < n; ++j) {
            float m = means[j];
            float v = inputs[j] - m;
            int lo = 0, hi = LVL;
            for (int s = 0; s < 8; ++s) {
                int mid = (lo + hi) >> 1;
                bool r = (s_uv[mid] < v);
                lo = r ? (mid + 1) : lo;
                hi = r ? hi : mid;
            }
            int idx = min(max(lo, 1), LVL - 1);
            float left = s_uv[idx - 1], right = s_uv[idx];
            bool tl = fabsf(v - left) <= fabsf(v - right);
            out_deq[j] = (tl ? left : right) + m;
            out_sym[j] = (float)(tl ? idx - 1 : idx);
        }
    }
}

extern "C" void kernel_launch(void* const* d_in, const int* in_sizes, int n_in,
                              void* d_out, int out_size, void* d_ws, size_t ws_size,
                              hipStream_t stream)
{
    const float* inputs = (const float*)d_in[0];
    const float* means  = (const float*)d_in[1];
    const float* uv     = (const float*)d_in[2];

    int n  = in_sizes[0];        // 12,582,912
    int n4 = n / 4;

    float* out     = (float*)d_out;
    float* out_deq = out;        // first N: dequant
    float* out_sym = out + n;    // second N: symbols (exact float values)

    size_t need = (size_t)NB * 2 * sizeof(float4);   // 16 KB
    if (d_ws != nullptr && ws_size >= need) {
        float4* lutA = (float4*)d_ws;
        float4* lutB = lutA + NB;
        agc_build_lut<<<(NB + 255) / 256, 256, 0, stream>>>(uv, lutA, lutB);

        int per_blk = 256 * QPT;                       // quads per block
        int nfull   = n4 / per_blk;                    // fully-covered blocks
        int blocks  = (n4 + per_blk - 1) / per_blk;    // 3072 for this shape
        if (blocks < 1) blocks = 1;
        agc_quant_lut<<<blocks, 256, 0, stream>>>(
            inputs, means, uv, lutA, lutB,
            out_deq, out_sym, n4, n, nfull);
    } else {
        int blocks = (n4 + 255) / 256;
        if (blocks < 1) blocks = 1;
        agc_quant_fallback<<<blocks, 256, 0, stream>>>(
            inputs, means, uv, out_deq, out_sym, n4, n);
    }
}